// Round 2
// baseline (353.607 us; speedup 1.0000x reference)
//
#include <hip/hip_runtime.h>
#include <stdint.h>

#define DEVI static __device__ __forceinline__

typedef __attribute__((ext_vector_type(4))) float f32x4;
typedef __attribute__((ext_vector_type(8))) __bf16 bf16x8;
typedef __attribute__((ext_vector_type(4))) uint16_t u16x4;
typedef uint16_t u16;

// ---------- helpers ----------
DEVI u16 f2bf(float f) {  // round-to-nearest-even fp32 -> bf16
  union { float f; uint32_t u; } v; v.f = f;
  uint32_t r = v.u + 0x7FFFu + ((v.u >> 16) & 1u);
  return (u16)(r >> 16);
}

DEVI f32x4 mfma16(bf16x8 a, bf16x8 b, f32x4 c) {
  return __builtin_amdgcn_mfma_f32_16x16x32_bf16(a, b, c, 0, 0, 0);
}

DEVI void load_lds16(const void* g, void* l) {  // async global->LDS, 16B/lane
  __builtin_amdgcn_global_load_lds(
      (const __attribute__((address_space(1))) void*)g,
      (__attribute__((address_space(3))) void*)l, 16, 0, 0);
}

DEVI bf16x8 lds_frag(const u16* p) { return *(const bf16x8*)p; }

// ---------- fp32 -> bf16 conversion (7 segments) ----------
#define NBIG (4 * 2048 * 1024)
#define NW (1024 * 1024)

__global__ __launch_bounds__(256) void cvt_kernel(
    const float* q, const float* k, const float* v, const float* Wq,
    const float* Wk, const float* Wv, const float* Wo, u16* qb, u16* kb,
    u16* vb, u16* Wqb, u16* Wkb, u16* Wvb, u16* Wob) {
  const float* src;
  u16* dst;
  int n;
  switch (blockIdx.y) {
    case 0: src = q;  dst = qb;  n = NBIG; break;
    case 1: src = k;  dst = kb;  n = NBIG; break;
    case 2: src = v;  dst = vb;  n = NBIG; break;
    case 3: src = Wq; dst = Wqb; n = NW;   break;
    case 4: src = Wk; dst = Wkb; n = NW;   break;
    case 5: src = Wv; dst = Wvb; n = NW;   break;
    default: src = Wo; dst = Wob; n = NW;  break;
  }
  int i = (blockIdx.x * 256 + threadIdx.x) * 4;
  if (i >= n) return;
  float4 f = *(const float4*)&src[i];
  u16x4 o;
  o.x = f2bf(f.x); o.y = f2bf(f.y); o.z = f2bf(f.z); o.w = f2bf(f.w);
  *(u16x4*)&dst[i] = o;
}

// ---------- GEMM core: C[128x128] tile of A[8192x1024] @ B[1024x1024]^T ----------
// m97 structure: BK=32, 256 thr = 4 waves (2x2), 16x16x32 bf16 MFMA, linear LDS,
// global_load_lds width 16, 2 barriers per K-step.  (UNCHANGED from round 1.)
DEVI void gemm_core_1024(const u16* __restrict__ A, const u16* __restrict__ Bm,
                         int bm, int bn, u16* As, u16* Bs, f32x4 acc[4][4]) {
  const int tid = threadIdx.x;
  const int w = tid >> 6, l = tid & 63;
  const int lr = l & 15, lg = l >> 4;
  const int wr = (w >> 1) * 64, wc = (w & 1) * 64;

  for (int i = 0; i < 4; ++i)
    for (int j = 0; j < 4; ++j) acc[i][j] = (f32x4){0.f, 0.f, 0.f, 0.f};

  // staging: 8 chunks of 1KB per matrix; wave w does chunks {2w, 2w+1}
  const int c0 = 2 * w, c1 = 2 * w + 1;
  const u16* gA0 = A + (size_t)(bm * 128 + c0 * 16 + (l >> 2)) * 1024 + (l & 3) * 8;
  const u16* gA1 = A + (size_t)(bm * 128 + c1 * 16 + (l >> 2)) * 1024 + (l & 3) * 8;
  const u16* gB0 = Bm + (size_t)(bn * 128 + c0 * 16 + (l >> 2)) * 1024 + (l & 3) * 8;
  const u16* gB1 = Bm + (size_t)(bn * 128 + c1 * 16 + (l >> 2)) * 1024 + (l & 3) * 8;
  u16* lA0 = As + c0 * 512;
  u16* lA1 = As + c1 * 512;
  u16* lB0 = Bs + c0 * 512;
  u16* lB1 = Bs + c1 * 512;

  int aoff[4], boff[4];
#pragma unroll
  for (int mi = 0; mi < 4; ++mi) aoff[mi] = (wr + mi * 16 + lr) * 32 + lg * 8;
#pragma unroll
  for (int nj = 0; nj < 4; ++nj) boff[nj] = (wc + nj * 16 + lr) * 32 + lg * 8;

  for (int k0 = 0; k0 < 1024; k0 += 32) {
    load_lds16(gA0 + k0, lA0);
    load_lds16(gA1 + k0, lA1);
    load_lds16(gB0 + k0, lB0);
    load_lds16(gB1 + k0, lB1);
    __syncthreads();  // compiler drains vmcnt before barrier
    bf16x8 af[4], bff[4];
#pragma unroll
    for (int mi = 0; mi < 4; ++mi) af[mi] = lds_frag(&As[aoff[mi]]);
#pragma unroll
    for (int nj = 0; nj < 4; ++nj) bff[nj] = lds_frag(&Bs[boff[nj]]);
#pragma unroll
    for (int mi = 0; mi < 4; ++mi)
#pragma unroll
      for (int nj = 0; nj < 4; ++nj)
        acc[mi][nj] = mfma16(af[mi], bff[nj], acc[mi][nj]);
    __syncthreads();
  }
}

// ---------- QKV projection: z=0/1/2 -> Q/K/V (UNCHANGED) ----------
__global__ __launch_bounds__(256) void proj_kernel(
    const u16* qb, const u16* kb, const u16* vb, const u16* Wq, const u16* Wk,
    const u16* Wv, const float* bq, const float* bk, const float* bv, u16* Qp,
    u16* Kp, u16* Vt) {
  __shared__ __align__(16) u16 As[128 * 32];
  __shared__ __align__(16) u16 Bs[128 * 32];
  const int z = blockIdx.z;
  const u16* A = z == 0 ? qb : z == 1 ? kb : vb;
  const u16* W = z == 0 ? Wq : z == 1 ? Wk : Wv;
  const float* bias = z == 0 ? bq : z == 1 ? bk : bv;

  f32x4 acc[4][4];
  gemm_core_1024(A, W, blockIdx.x, blockIdx.y, As, Bs, acc);

  const int tid = threadIdx.x;
  const int w = tid >> 6, l = tid & 63;
  const int lr = l & 15, lg = l >> 4;
  const int wr = (w >> 1) * 64, wc = (w & 1) * 64;
  const int b = (blockIdx.x * 128) >> 11;  // blocks never straddle batches

#pragma unroll
  for (int nj = 0; nj < 4; ++nj) {
    const int col = blockIdx.y * 128 + wc + nj * 16 + lr;
    const float bb = bias[col];
    const int h = col >> 6, d = col & 63;
#pragma unroll
    for (int mi = 0; mi < 4; ++mi) {
      const int m0 = blockIdx.x * 128 + wr + mi * 16 + lg * 4;
      const int s0 = m0 & 2047;
      if (z < 2) {
        u16* dst = (z == 0) ? Qp : Kp;
#pragma unroll
        for (int r = 0; r < 4; ++r)
          dst[(((size_t)(b * 16 + h) * 2048) + s0 + r) * 64 + d] =
              f2bf(acc[mi][nj][r] + bb);
      } else {
        u16x4 pk;
        pk.x = f2bf(acc[mi][nj][0] + bb);
        pk.y = f2bf(acc[mi][nj][1] + bb);
        pk.z = f2bf(acc[mi][nj][2] + bb);
        pk.w = f2bf(acc[mi][nj][3] + bb);
        *(u16x4*)&Vt[(((size_t)(b * 16 + h) * 64) + d) * 2048 + s0] = pk;
      }
    }
  }
}

// ---------- output projection -> fp32 d_out (UNCHANGED) ----------
__global__ __launch_bounds__(256) void outproj_kernel(const u16* O,
                                                      const u16* Wo,
                                                      const float* bo,
                                                      float* out) {
  __shared__ __align__(16) u16 As[128 * 32];
  __shared__ __align__(16) u16 Bs[128 * 32];
  f32x4 acc[4][4];
  gemm_core_1024(O, Wo, blockIdx.x, blockIdx.y, As, Bs, acc);

  const int tid = threadIdx.x;
  const int w = tid >> 6, l = tid & 63;
  const int lr = l & 15, lg = l >> 4;
  const int wr = (w >> 1) * 64, wc = (w & 1) * 64;
#pragma unroll
  for (int nj = 0; nj < 4; ++nj) {
    const int col = blockIdx.y * 128 + wc + nj * 16 + lr;
    const float bb = bo[col];
#pragma unroll
    for (int mi = 0; mi < 4; ++mi) {
      const int m0 = blockIdx.x * 128 + wr + mi * 16 + lg * 4;
#pragma unroll
      for (int r = 0; r < 4; ++r)
        out[(size_t)(m0 + r) * 1024 + col] = acc[mi][nj][r] + bb;
    }
  }
}

// ---------- flash attention (SIMPLIFIED: reg-staged K/V, padded unswizzled LDS) ----
// grid (S/64, B*H). 256 thr = 4 waves, wave w owns q-rows [q0+16w, q0+16w+16).
// K tile [64][72] (pad +8 -> 2-way bank aliasing only), V tile [64][72] from
// transposed Vt, per-wave P tile [16][72]. No global_load_lds, no XOR swizzle:
// isolation build to locate the round-1 0.026 absmax bug.
#define LDP 72
__global__ __launch_bounds__(256) void attn_kernel(const u16* Qp, const u16* Kp,
                                                   const u16* Vt, u16* O) {
  __shared__ __align__(16) u16 Kl[64 * LDP];
  __shared__ __align__(16) u16 Vl[64 * LDP];
  __shared__ __align__(16) u16 Pl[4 * 16 * LDP];

  const int tid = threadIdx.x, w = tid >> 6, l = tid & 63;
  const int lr = l & 15, lg = l >> 4;
  const int bh = blockIdx.y;
  const int q0 = blockIdx.x * 64;
  const u16* Qh = Qp + (size_t)bh * 2048 * 64;
  const u16* Kh = Kp + (size_t)bh * 2048 * 64;
  const u16* Vh = Vt + (size_t)bh * 64 * 2048;

  // Q fragments in registers (wave-private rows)
  bf16x8 qa[2];
#pragma unroll
  for (int ks = 0; ks < 2; ++ks)
    qa[ks] = *(const bf16x8*)&Qh[(size_t)(q0 + w * 16 + lr) * 64 + ks * 32 + lg * 8];

  f32x4 o[4];
#pragma unroll
  for (int i = 0; i < 4; ++i) o[i] = (f32x4){0.f, 0.f, 0.f, 0.f};
  float mrow[4], lrow[4];
#pragma unroll
  for (int r = 0; r < 4; ++r) { mrow[r] = -3.0e38f; lrow[r] = 0.f; }

  // staging map: element-chunks e = tid, tid+256 over 512 chunks of 8 elems
  const int r0 = tid >> 3, g0 = tid & 7;
  const int r1 = (tid + 256) >> 3, g1 = tid & 7;

  // plain LDS read offsets (row-major, stride LDP)
  int kvoff[4][2], poff[2];
#pragma unroll
  for (int nf = 0; nf < 4; ++nf)
#pragma unroll
    for (int ks = 0; ks < 2; ++ks)
      kvoff[nf][ks] = (nf * 16 + lr) * LDP + (ks * 4 + lg) * 8;
#pragma unroll
  for (int ks = 0; ks < 2; ++ks)
    poff[ks] = w * 16 * LDP + lr * LDP + (ks * 4 + lg) * 8;

  for (int kt = 0; kt < 32; ++kt) {
    // load this tile's K/V to registers (plain coalesced bf16x8 loads)
    bf16x8 kv0 = *(const bf16x8*)&Kh[kt * 4096 + r0 * 64 + g0 * 8];
    bf16x8 kv1 = *(const bf16x8*)&Kh[kt * 4096 + r1 * 64 + g1 * 8];
    bf16x8 vv0 = *(const bf16x8*)&Vh[(size_t)r0 * 2048 + kt * 64 + g0 * 8];
    bf16x8 vv1 = *(const bf16x8*)&Vh[(size_t)r1 * 2048 + kt * 64 + g1 * 8];
    __syncthreads();  // all waves done reading previous tile
    *(bf16x8*)&Kl[r0 * LDP + g0 * 8] = kv0;
    *(bf16x8*)&Kl[r1 * LDP + g1 * 8] = kv1;
    *(bf16x8*)&Vl[r0 * LDP + g0 * 8] = vv0;
    *(bf16x8*)&Vl[r1 * LDP + g1 * 8] = vv1;
    __syncthreads();  // staging visible

    // ---- S = Q K^T ----
    f32x4 sa[4];
#pragma unroll
    for (int nf = 0; nf < 4; ++nf) sa[nf] = (f32x4){0.f, 0.f, 0.f, 0.f};
#pragma unroll
    for (int ks = 0; ks < 2; ++ks)
#pragma unroll
      for (int nf = 0; nf < 4; ++nf)
        sa[nf] = mfma16(qa[ks], lds_frag(&Kl[kvoff[nf][ks]]), sa[nf]);

    // ---- online softmax (row = lg*4+r, cols across lanes lr and nf) ----
    float p[4][4], alpha[4];
#pragma unroll
    for (int r = 0; r < 4; ++r) {
      float mx = fmaxf(fmaxf(sa[0][r], sa[1][r]), fmaxf(sa[2][r], sa[3][r]));
#pragma unroll
      for (int msk = 1; msk < 16; msk <<= 1) mx = fmaxf(mx, __shfl_xor(mx, msk, 64));
      const float newm = fmaxf(mrow[r], mx * 0.125f);
      alpha[r] = __expf(mrow[r] - newm);
      float rs = 0.f;
#pragma unroll
      for (int nf = 0; nf < 4; ++nf) {
        const float pv = __expf(sa[nf][r] * 0.125f - newm);
        p[nf][r] = pv;
        rs += pv;
      }
#pragma unroll
      for (int msk = 1; msk < 16; msk <<= 1) rs += __shfl_xor(rs, msk, 64);
      lrow[r] = lrow[r] * alpha[r] + rs;
      mrow[r] = newm;
    }
#pragma unroll
    for (int df = 0; df < 4; ++df)
#pragma unroll
      for (int r = 0; r < 4; ++r) o[df][r] *= alpha[r];

    // ---- P -> LDS (C/D layout -> A-frag layout), plain row-major write ----
#pragma unroll
    for (int nf = 0; nf < 4; ++nf)
#pragma unroll
      for (int r = 0; r < 4; ++r) {
        const int prow = lg * 4 + r;
        Pl[w * 16 * LDP + prow * LDP + nf * 16 + lr] = f2bf(p[nf][r]);
      }
    bf16x8 pa[2];
#pragma unroll
    for (int ks = 0; ks < 2; ++ks) pa[ks] = lds_frag(&Pl[poff[ks]]);

    // ---- O += P V ----
#pragma unroll
    for (int ks = 0; ks < 2; ++ks)
#pragma unroll
      for (int df = 0; df < 4; ++df)
        o[df] = mfma16(pa[ks], lds_frag(&Vl[kvoff[df][ks]]), o[df]);
  }

  // ---- epilogue: O[b, s, h*64+d] bf16 ----
  const int b = bh >> 4, h = bh & 15;
#pragma unroll
  for (int df = 0; df < 4; ++df) {
    const int col = h * 64 + df * 16 + lr;
#pragma unroll
    for (int r = 0; r < 4; ++r) {
      const int s = q0 + w * 16 + lg * 4 + r;
      O[((size_t)(b * 2048 + s)) * 1024 + col] = f2bf(o[df][r] / lrow[r]);
    }
  }
}

// ---------- launcher ----------
extern "C" void kernel_launch(void* const* d_in, const int* in_sizes, int n_in,
                              void* d_out, int out_size, void* d_ws,
                              size_t ws_size, hipStream_t stream) {
  const float* q  = (const float*)d_in[0];
  const float* k  = (const float*)d_in[1];
  const float* v  = (const float*)d_in[2];
  const float* Wq = (const float*)d_in[3];
  const float* bq = (const float*)d_in[4];
  const float* Wk = (const float*)d_in[5];
  const float* bk = (const float*)d_in[6];
  const float* Wv = (const float*)d_in[7];
  const float* bv = (const float*)d_in[8];
  const float* Wo = (const float*)d_in[9];
  const float* bo = (const float*)d_in[10];
  float* out = (float*)d_out;

  u16* ws = (u16*)d_ws;
  u16* qb  = ws;              // [8192,1024] bf16
  u16* kb  = qb + NBIG;
  u16* vb  = kb + NBIG;
  u16* Wqb = vb + NBIG;       // [1024,1024] bf16 x4
  u16* Wkb = Wqb + NW;
  u16* Wvb = Wkb + NW;
  u16* Wob = Wvb + NW;
  u16* Qp  = Wob + NW;        // [B,H,S,64]
  u16* Kp  = Qp + NBIG;       // [B,H,S,64]
  u16* Vt  = Kp + NBIG;       // [B,H,64,S]
  u16* O   = qb;              // alias: qb dead after proj_kernel

  cvt_kernel<<<dim3(8192, 7, 1), 256, 0, stream>>>(q, k, v, Wq, Wk, Wv, Wo, qb,
                                                   kb, vb, Wqb, Wkb, Wvb, Wob);
  proj_kernel<<<dim3(64, 8, 3), 256, 0, stream>>>(qb, kb, vb, Wqb, Wkb, Wvb,
                                                  bq, bk, bv, Qp, Kp, Vt);
  attn_kernel<<<dim3(32, 64, 1), 256, 0, stream>>>(Qp, Kp, Vt, O);
  outproj_kernel<<<dim3(64, 8, 1), 256, 0, stream>>>(O, Wob, bo, out);
}

// Round 4
// 271.498 us; speedup vs baseline: 1.3024x; 1.3024x over previous
//
#include <hip/hip_runtime.h>
#include <stdint.h>

#define DEVI static __device__ __forceinline__

typedef __attribute__((ext_vector_type(4))) float f32x4;
typedef __attribute__((ext_vector_type(16))) float f32x16;
typedef __attribute__((ext_vector_type(8))) __bf16 bf16x8;
typedef __attribute__((ext_vector_type(4))) uint16_t u16x4;
typedef uint16_t u16;

// ---------- helpers ----------
DEVI u16 f2bf(float f) {  // round-to-nearest-even fp32 -> bf16
  union { float f; uint32_t u; } v; v.f = f;
  uint32_t r = v.u + 0x7FFFu + ((v.u >> 16) & 1u);
  return (u16)(r >> 16);
}

DEVI f32x4 mfma16(bf16x8 a, bf16x8 b, f32x4 c) {
  return __builtin_amdgcn_mfma_f32_16x16x32_bf16(a, b, c, 0, 0, 0);
}

DEVI f32x16 mfma32(bf16x8 a, bf16x8 b, f32x16 c) {
  return __builtin_amdgcn_mfma_f32_32x32x16_bf16(a, b, c, 0, 0, 0);
}

DEVI void load_lds16(const void* g, void* l) {  // async global->LDS, 16B/lane
  __builtin_amdgcn_global_load_lds(
      (const __attribute__((address_space(1))) void*)g,
      (__attribute__((address_space(3))) void*)l, 16, 0, 0);
}

DEVI bf16x8 lds_frag(const u16* p) { return *(const bf16x8*)p; }

DEVI f32x16 zero16() {
  f32x16 z;
#pragma unroll
  for (int i = 0; i < 16; ++i) z[i] = 0.f;
  return z;
}

// cross-half exchange via shfl (semantics-safe; no asm operand hazards)
DEVI float partner_f(float x) { return __shfl_xor(x, 32, 64); }
DEVI uint32_t partner_u(uint32_t x) {
  return (uint32_t)__shfl_xor((int)x, 32, 64);
}

// emulated v_permlane32_swap_b32 (V1): a' = [a.lo | b.lo], b' = [a.hi | b.hi]
DEVI void pswap_emul(uint32_t& a, uint32_t& b, bool hib) {
  const uint32_t sa = partner_u(a), sb = partner_u(b);
  const uint32_t na = hib ? sb : a;   // hi lanes take partner's b; lo keep a
  const uint32_t nb = hib ? b : sa;   // lo lanes take partner's a; hi keep b
  a = na;
  b = nb;
}

DEVI uint32_t pk2(float a, float b) {  // pack 2 fp32 -> 2 bf16 (RNE via HW cvt)
  union { __bf16 h; u16 u; } x, y;
  x.h = (__bf16)a; y.h = (__bf16)b;
  return ((uint32_t)y.u << 16) | (uint32_t)x.u;
}

// ---------- fp32 -> bf16 conversion (7 segments) ----------
#define NBIG (4 * 2048 * 1024)
#define NW (1024 * 1024)

__global__ __launch_bounds__(256) void cvt_kernel(
    const float* q, const float* k, const float* v, const float* Wq,
    const float* Wk, const float* Wv, const float* Wo, u16* qb, u16* kb,
    u16* vb, u16* Wqb, u16* Wkb, u16* Wvb, u16* Wob) {
  const float* src;
  u16* dst;
  int n;
  switch (blockIdx.y) {
    case 0: src = q;  dst = qb;  n = NBIG; break;
    case 1: src = k;  dst = kb;  n = NBIG; break;
    case 2: src = v;  dst = vb;  n = NBIG; break;
    case 3: src = Wq; dst = Wqb; n = NW;   break;
    case 4: src = Wk; dst = Wkb; n = NW;   break;
    case 5: src = Wv; dst = Wvb; n = NW;   break;
    default: src = Wo; dst = Wob; n = NW;  break;
  }
  int i = (blockIdx.x * 256 + threadIdx.x) * 4;
  if (i >= n) return;
  float4 f = *(const float4*)&src[i];
  u16x4 o;
  o.x = f2bf(f.x); o.y = f2bf(f.y); o.z = f2bf(f.z); o.w = f2bf(f.w);
  *(u16x4*)&dst[i] = o;
}

// ---------- GEMM core (m97 structure, UNCHANGED) ----------
DEVI void gemm_core_1024(const u16* __restrict__ A, const u16* __restrict__ Bm,
                         int bm, int bn, u16* As, u16* Bs, f32x4 acc[4][4]) {
  const int tid = threadIdx.x;
  const int w = tid >> 6, l = tid & 63;
  const int lr = l & 15, lg = l >> 4;
  const int wr = (w >> 1) * 64, wc = (w & 1) * 64;

  for (int i = 0; i < 4; ++i)
    for (int j = 0; j < 4; ++j) acc[i][j] = (f32x4){0.f, 0.f, 0.f, 0.f};

  const int c0 = 2 * w, c1 = 2 * w + 1;
  const u16* gA0 = A + (size_t)(bm * 128 + c0 * 16 + (l >> 2)) * 1024 + (l & 3) * 8;
  const u16* gA1 = A + (size_t)(bm * 128 + c1 * 16 + (l >> 2)) * 1024 + (l & 3) * 8;
  const u16* gB0 = Bm + (size_t)(bn * 128 + c0 * 16 + (l >> 2)) * 1024 + (l & 3) * 8;
  const u16* gB1 = Bm + (size_t)(bn * 128 + c1 * 16 + (l >> 2)) * 1024 + (l & 3) * 8;
  u16* lA0 = As + c0 * 512;
  u16* lA1 = As + c1 * 512;
  u16* lB0 = Bs + c0 * 512;
  u16* lB1 = Bs + c1 * 512;

  int aoff[4], boff[4];
#pragma unroll
  for (int mi = 0; mi < 4; ++mi) aoff[mi] = (wr + mi * 16 + lr) * 32 + lg * 8;
#pragma unroll
  for (int nj = 0; nj < 4; ++nj) boff[nj] = (wc + nj * 16 + lr) * 32 + lg * 8;

  for (int k0 = 0; k0 < 1024; k0 += 32) {
    load_lds16(gA0 + k0, lA0);
    load_lds16(gA1 + k0, lA1);
    load_lds16(gB0 + k0, lB0);
    load_lds16(gB1 + k0, lB1);
    __syncthreads();
    bf16x8 af[4], bff[4];
#pragma unroll
    for (int mi = 0; mi < 4; ++mi) af[mi] = lds_frag(&As[aoff[mi]]);
#pragma unroll
    for (int nj = 0; nj < 4; ++nj) bff[nj] = lds_frag(&Bs[boff[nj]]);
#pragma unroll
    for (int mi = 0; mi < 4; ++mi)
#pragma unroll
      for (int nj = 0; nj < 4; ++nj)
        acc[mi][nj] = mfma16(af[mi], bff[nj], acc[mi][nj]);
    __syncthreads();
  }
}

// ---------- QKV projection (UNCHANGED) ----------
__global__ __launch_bounds__(256) void proj_kernel(
    const u16* qb, const u16* kb, const u16* vb, const u16* Wq, const u16* Wk,
    const u16* Wv, const float* bq, const float* bk, const float* bv, u16* Qp,
    u16* Kp, u16* Vt) {
  __shared__ __align__(16) u16 As[128 * 32];
  __shared__ __align__(16) u16 Bs[128 * 32];
  const int z = blockIdx.z;
  const u16* A = z == 0 ? qb : z == 1 ? kb : vb;
  const u16* W = z == 0 ? Wq : z == 1 ? Wk : Wv;
  const float* bias = z == 0 ? bq : z == 1 ? bk : bv;

  f32x4 acc[4][4];
  gemm_core_1024(A, W, blockIdx.x, blockIdx.y, As, Bs, acc);

  const int tid = threadIdx.x;
  const int w = tid >> 6, l = tid & 63;
  const int lr = l & 15, lg = l >> 4;
  const int wr = (w >> 1) * 64, wc = (w & 1) * 64;
  const int b = (blockIdx.x * 128) >> 11;

#pragma unroll
  for (int nj = 0; nj < 4; ++nj) {
    const int col = blockIdx.y * 128 + wc + nj * 16 + lr;
    const float bb = bias[col];
    const int h = col >> 6, d = col & 63;
#pragma unroll
    for (int mi = 0; mi < 4; ++mi) {
      const int m0 = blockIdx.x * 128 + wr + mi * 16 + lg * 4;
      const int s0 = m0 & 2047;
      if (z < 2) {
        u16* dst = (z == 0) ? Qp : Kp;
#pragma unroll
        for (int r = 0; r < 4; ++r)
          dst[(((size_t)(b * 16 + h) * 2048) + s0 + r) * 64 + d] =
              f2bf(acc[mi][nj][r] + bb);
      } else {
        u16x4 pk;
        pk.x = f2bf(acc[mi][nj][0] + bb);
        pk.y = f2bf(acc[mi][nj][1] + bb);
        pk.z = f2bf(acc[mi][nj][2] + bb);
        pk.w = f2bf(acc[mi][nj][3] + bb);
        *(u16x4*)&Vt[(((size_t)(b * 16 + h) * 64) + d) * 2048 + s0] = pk;
      }
    }
  }
}

// ---------- output projection (UNCHANGED) ----------
__global__ __launch_bounds__(256) void outproj_kernel(const u16* O,
                                                      const u16* Wo,
                                                      const float* bo,
                                                      float* out) {
  __shared__ __align__(16) u16 As[128 * 32];
  __shared__ __align__(16) u16 Bs[128 * 32];
  f32x4 acc[4][4];
  gemm_core_1024(O, Wo, blockIdx.x, blockIdx.y, As, Bs, acc);

  const int tid = threadIdx.x;
  const int w = tid >> 6, l = tid & 63;
  const int lr = l & 15, lg = l >> 4;
  const int wr = (w >> 1) * 64, wc = (w & 1) * 64;
#pragma unroll
  for (int nj = 0; nj < 4; ++nj) {
    const int col = blockIdx.y * 128 + wc + nj * 16 + lr;
    const float bb = bo[col];
#pragma unroll
    for (int mi = 0; mi < 4; ++mi) {
      const int m0 = blockIdx.x * 128 + wr + mi * 16 + lg * 4;
#pragma unroll
      for (int r = 0; r < 4; ++r)
        out[(size_t)(m0 + r) * 1024 + col] = acc[mi][nj][r] + bb;
    }
  }
}

// ---------- flash attention v3: swapped QK^T, 32x32x16, in-register softmax,
// ALL cross-half moves via __shfl_xor(.,32) (no permlane asm) ----------
#define LDPK 72
#define NT 32  // 2048 / 64
__global__ __launch_bounds__(256) void attn_kernel(const u16* Qp, const u16* Kp,
                                                   const u16* Vt, u16* Ob) {
  __shared__ __align__(16) u16 Kl[64 * LDPK];
  __shared__ __align__(16) u16 Vl[64 * LDPK];

  const int tid = threadIdx.x, w = tid >> 6, l = tid & 63;
  const int q = l & 31, hi = l >> 5;
  const bool hib = hi != 0;
  const int bh = blockIdx.y;
  const int q0 = blockIdx.x * 128 + w * 32;
  const u16* Qh = Qp + (size_t)bh * 2048 * 64;
  const u16* Kh = Kp + (size_t)bh * 2048 * 64;
  const u16* Vh = Vt + (size_t)bh * 64 * 2048;

  // Q B-fragments (held all kernel): qf[ds] = Q[q0+q][ds*16 + hi*8 .. +8]
  bf16x8 qf[4];
#pragma unroll
  for (int ds = 0; ds < 4; ++ds)
    qf[ds] = *(const bf16x8*)&Qh[(size_t)(q0 + q) * 64 + ds * 16 + hi * 8];

  f32x16 o0 = zero16(), o1 = zero16();
  float m = -1.0e30f, ln = 0.f;

  // staging map: rows r0 (0..31) / r1 (32..63), col chunk g0
  const int r0 = tid >> 3, g0 = tid & 7;
  const int r1 = r0 + 32;

  int koff[2][4], voff[2][4];
#pragma unroll
  for (int kb = 0; kb < 2; ++kb)
#pragma unroll
    for (int ds = 0; ds < 4; ++ds)
      koff[kb][ds] = (kb * 32 + q) * LDPK + ds * 16 + hi * 8;
#pragma unroll
  for (int db = 0; db < 2; ++db)
#pragma unroll
    for (int ks = 0; ks < 4; ++ks)
      voff[db][ks] = (db * 32 + q) * LDPK + ks * 16 + hi * 8;

  // prologue: tile 0 -> regs
  bf16x8 kv0 = *(const bf16x8*)&Kh[r0 * 64 + g0 * 8];
  bf16x8 kv1 = *(const bf16x8*)&Kh[r1 * 64 + g0 * 8];
  bf16x8 vv0 = *(const bf16x8*)&Vh[(size_t)r0 * 2048 + g0 * 8];
  bf16x8 vv1 = *(const bf16x8*)&Vh[(size_t)r1 * 2048 + g0 * 8];

  for (int kt = 0; kt < NT; ++kt) {
    __syncthreads();  // all waves done reading previous tile
    *(bf16x8*)&Kl[r0 * LDPK + g0 * 8] = kv0;
    *(bf16x8*)&Kl[r1 * LDPK + g0 * 8] = kv1;
    *(bf16x8*)&Vl[r0 * LDPK + g0 * 8] = vv0;
    *(bf16x8*)&Vl[r1 * LDPK + g0 * 8] = vv1;
    __syncthreads();  // staging visible

    // T14: issue next tile's global loads now; latency hides under compute
    if (kt + 1 < NT) {
      const int ko = (kt + 1) * 4096, vo = (kt + 1) * 64;
      kv0 = *(const bf16x8*)&Kh[ko + r0 * 64 + g0 * 8];
      kv1 = *(const bf16x8*)&Kh[ko + r1 * 64 + g0 * 8];
      vv0 = *(const bf16x8*)&Vh[(size_t)r0 * 2048 + vo + g0 * 8];
      vv1 = *(const bf16x8*)&Vh[(size_t)r1 * 2048 + vo + g0 * 8];
    }

    // ---- S^T = K Q^T : c_t[reg] = S[k = t*32 + krow(reg,hi)][q] ----
    f32x16 c0 = zero16(), c1 = zero16();
#pragma unroll
    for (int ds = 0; ds < 4; ++ds)
      c0 = mfma32(lds_frag(&Kl[koff[0][ds]]), qf[ds], c0);
#pragma unroll
    for (int ds = 0; ds < 4; ++ds)
      c1 = mfma32(lds_frag(&Kl[koff[1][ds]]), qf[ds], c1);

    // ---- online softmax, lane-local + cross-half shfl combine ----
    float pv[32];
#pragma unroll
    for (int r = 0; r < 16; ++r) {
      pv[r] = c0[r] * 0.125f;
      pv[16 + r] = c1[r] * 0.125f;
    }
    float mx = pv[0];
#pragma unroll
    for (int r = 1; r < 32; ++r) mx = fmaxf(mx, pv[r]);
    mx = fmaxf(mx, partner_f(mx));  // combine with partner half
    const float mnew = fmaxf(m, mx);
    const float alpha = __expf(m - mnew);
    m = mnew;
    float rs = 0.f;
#pragma unroll
    for (int r = 0; r < 32; ++r) {
      pv[r] = __expf(pv[r] - mnew);
      rs += pv[r];
    }
    rs += partner_f(rs);
    ln = ln * alpha + rs;
#pragma unroll
    for (int r = 0; r < 16; ++r) { o0[r] *= alpha; o1[r] *= alpha; }

    // ---- P -> bf16 pair-words, V1-pswap(emulated) into PV B-fragments ----
    uint32_t wv[16];
#pragma unroll
    for (int i = 0; i < 8; ++i) {
      wv[i]     = pk2(pv[2 * i], pv[2 * i + 1]);
      wv[8 + i] = pk2(pv[16 + 2 * i], pv[16 + 2 * i + 1]);
    }
    bf16x8 pa[4];
#pragma unroll
    for (int ks = 0; ks < 4; ++ks) {
      const int base = (ks >> 1) * 8 + 4 * (ks & 1);
      uint32_t x0 = wv[base],     y0 = wv[base + 2];
      uint32_t x1 = wv[base + 1], y1 = wv[base + 3];
      pswap_emul(x0, y0, hib);
      pswap_emul(x1, y1, hib);
      union { uint32_t u[4]; bf16x8 v; } cvt;
      cvt.u[0] = x0; cvt.u[1] = x1; cvt.u[2] = y0; cvt.u[3] = y1;
      pa[ks] = cvt.v;
    }

    // ---- O^T += V^T P^T ----
#pragma unroll
    for (int ks = 0; ks < 4; ++ks)
      o0 = mfma32(lds_frag(&Vl[voff[0][ks]]), pa[ks], o0);
#pragma unroll
    for (int ks = 0; ks < 4; ++ks)
      o1 = mfma32(lds_frag(&Vl[voff[1][ks]]), pa[ks], o1);
  }

  // ---- epilogue: lane holds row s = q0+q; d = db*32 + (r&3)+8*(r>>2)+4*hi ----
  const int b2 = bh >> 4, h = bh & 15;
  const float inv = 1.0f / ln;
  u16* orow = Ob + ((size_t)(b2 * 2048 + q0 + q)) * 1024 + h * 64;
#pragma unroll
  for (int g = 0; g < 4; ++g) {
    u16x4 pk;
    pk.x = f2bf(o0[4 * g + 0] * inv);
    pk.y = f2bf(o0[4 * g + 1] * inv);
    pk.z = f2bf(o0[4 * g + 2] * inv);
    pk.w = f2bf(o0[4 * g + 3] * inv);
    *(u16x4*)&orow[8 * g + 4 * hi] = pk;
  }
#pragma unroll
  for (int g = 0; g < 4; ++g) {
    u16x4 pk;
    pk.x = f2bf(o1[4 * g + 0] * inv);
    pk.y = f2bf(o1[4 * g + 1] * inv);
    pk.z = f2bf(o1[4 * g + 2] * inv);
    pk.w = f2bf(o1[4 * g + 3] * inv);
    *(u16x4*)&orow[32 + 8 * g + 4 * hi] = pk;
  }
}

// ---------- launcher ----------
extern "C" void kernel_launch(void* const* d_in, const int* in_sizes, int n_in,
                              void* d_out, int out_size, void* d_ws,
                              size_t ws_size, hipStream_t stream) {
  const float* q  = (const float*)d_in[0];
  const float* k  = (const float*)d_in[1];
  const float* v  = (const float*)d_in[2];
  const float* Wq = (const float*)d_in[3];
  const float* bq = (const float*)d_in[4];
  const float* Wk = (const float*)d_in[5];
  const float* bk = (const float*)d_in[6];
  const float* Wv = (const float*)d_in[7];
  const float* bv = (const float*)d_in[8];
  const float* Wo = (const float*)d_in[9];
  const float* bo = (const float*)d_in[10];
  float* out = (float*)d_out;

  u16* ws = (u16*)d_ws;
  u16* qb  = ws;              // [8192,1024] bf16
  u16* kb  = qb + NBIG;
  u16* vb  = kb + NBIG;
  u16* Wqb = vb + NBIG;       // [1024,1024] bf16 x4
  u16* Wkb = Wqb + NW;
  u16* Wvb = Wkb + NW;
  u16* Wob = Wvb + NW;
  u16* Qp  = Wob + NW;        // [B,H,S,64]
  u16* Kp  = Qp + NBIG;       // [B,H,S,64]
  u16* Vt  = Kp + NBIG;       // [B,H,64,S]
  u16* O   = qb;              // alias: qb dead after proj_kernel

  cvt_kernel<<<dim3(8192, 7, 1), 256, 0, stream>>>(q, k, v, Wq, Wk, Wv, Wo, qb,
                                                   kb, vb, Wqb, Wkb, Wvb, Wob);
  proj_kernel<<<dim3(64, 8, 3), 256, 0, stream>>>(qb, kb, vb, Wqb, Wkb, Wvb,
                                                  bq, bk, bv, Qp, Kp, Vt);
  attn_kernel<<<dim3(16, 64, 1), 256, 0, stream>>>(Qp, Kp, Vt, O);
  outproj_kernel<<<dim3(64, 8, 1), 256, 0, stream>>>(O, Wob, bo, out);
}

// Round 5
// 238.607 us; speedup vs baseline: 1.4820x; 1.1378x over previous
//
#include <hip/hip_runtime.h>
#include <stdint.h>

#define DEVI static __device__ __forceinline__

typedef __attribute__((ext_vector_type(4))) float f32x4;
typedef __attribute__((ext_vector_type(16))) float f32x16;
typedef __attribute__((ext_vector_type(8))) __bf16 bf16x8;
typedef __attribute__((ext_vector_type(4))) uint16_t u16x4;
typedef uint16_t u16;

// ---------- helpers ----------
DEVI u16 f2bf(float f) {  // round-to-nearest-even fp32 -> bf16
  union { float f; uint32_t u; } v; v.f = f;
  uint32_t r = v.u + 0x7FFFu + ((v.u >> 16) & 1u);
  return (u16)(r >> 16);
}

DEVI f32x4 mfma16(bf16x8 a, bf16x8 b, f32x4 c) {
  return __builtin_amdgcn_mfma_f32_16x16x32_bf16(a, b, c, 0, 0, 0);
}

DEVI f32x16 mfma32(bf16x8 a, bf16x8 b, f32x16 c) {
  return __builtin_amdgcn_mfma_f32_32x32x16_bf16(a, b, c, 0, 0, 0);
}

DEVI void load_lds16(const void* g, void* l) {  // async global->LDS, 16B/lane
  __builtin_amdgcn_global_load_lds(
      (const __attribute__((address_space(1))) void*)g,
      (__attribute__((address_space(3))) void*)l, 16, 0, 0);
}

DEVI bf16x8 lds_frag(const u16* p) { return *(const bf16x8*)p; }

DEVI f32x16 zero16() {
  f32x16 z;
#pragma unroll
  for (int i = 0; i < 16; ++i) z[i] = 0.f;
  return z;
}

// hardware exp2 (1 instruction; denorm tails flush to 0, which is what we want)
DEVI float exp2_hw(float x) {
  float r;
  asm("v_exp_f32 %0, %1" : "=v"(r) : "v"(x));
  return r;
}

// pack 2 f32 -> bf16x2 word in ONE instruction (T12 recipe; distinct operands)
DEVI uint32_t cvtpk(float lo, float hi) {
  uint32_t r;
  asm("v_cvt_pk_bf16_f32 %0, %1, %2" : "=v"(r) : "v"(lo), "v"(hi));
  return r;
}

// cross-half exchange via shfl (semantics-safe; no asm operand hazards)
DEVI float partner_f(float x) { return __shfl_xor(x, 32, 64); }
DEVI uint32_t partner_u(uint32_t x) {
  return (uint32_t)__shfl_xor((int)x, 32, 64);
}

// emulated v_permlane32_swap_b32 (V1): a' = [a.lo | b.lo], b' = [a.hi | b.hi]
DEVI void pswap_emul(uint32_t& a, uint32_t& b, bool hib) {
  const uint32_t sa = partner_u(a), sb = partner_u(b);
  const uint32_t na = hib ? sb : a;   // hi lanes take partner's b; lo keep a
  const uint32_t nb = hib ? b : sa;   // lo lanes take partner's a; hi keep b
  a = na;
  b = nb;
}

// ---------- fp32 -> bf16 conversion (7 segments) ----------
#define NBIG (4 * 2048 * 1024)
#define NW (1024 * 1024)

__global__ __launch_bounds__(256) void cvt_kernel(
    const float* q, const float* k, const float* v, const float* Wq,
    const float* Wk, const float* Wv, const float* Wo, u16* qb, u16* kb,
    u16* vb, u16* Wqb, u16* Wkb, u16* Wvb, u16* Wob) {
  const float* src;
  u16* dst;
  int n;
  switch (blockIdx.y) {
    case 0: src = q;  dst = qb;  n = NBIG; break;
    case 1: src = k;  dst = kb;  n = NBIG; break;
    case 2: src = v;  dst = vb;  n = NBIG; break;
    case 3: src = Wq; dst = Wqb; n = NW;   break;
    case 4: src = Wk; dst = Wkb; n = NW;   break;
    case 5: src = Wv; dst = Wvb; n = NW;   break;
    default: src = Wo; dst = Wob; n = NW;  break;
  }
  int i = (blockIdx.x * 256 + threadIdx.x) * 4;
  if (i >= n) return;
  float4 f = *(const float4*)&src[i];
  u16x4 o;
  o.x = f2bf(f.x); o.y = f2bf(f.y); o.z = f2bf(f.z); o.w = f2bf(f.w);
  *(u16x4*)&dst[i] = o;
}

// ---------- GEMM core (m97 structure, UNCHANGED) ----------
DEVI void gemm_core_1024(const u16* __restrict__ A, const u16* __restrict__ Bm,
                         int bm, int bn, u16* As, u16* Bs, f32x4 acc[4][4]) {
  const int tid = threadIdx.x;
  const int w = tid >> 6, l = tid & 63;
  const int lr = l & 15, lg = l >> 4;
  const int wr = (w >> 1) * 64, wc = (w & 1) * 64;

  for (int i = 0; i < 4; ++i)
    for (int j = 0; j < 4; ++j) acc[i][j] = (f32x4){0.f, 0.f, 0.f, 0.f};

  const int c0 = 2 * w, c1 = 2 * w + 1;
  const u16* gA0 = A + (size_t)(bm * 128 + c0 * 16 + (l >> 2)) * 1024 + (l & 3) * 8;
  const u16* gA1 = A + (size_t)(bm * 128 + c1 * 16 + (l >> 2)) * 1024 + (l & 3) * 8;
  const u16* gB0 = Bm + (size_t)(bn * 128 + c0 * 16 + (l >> 2)) * 1024 + (l & 3) * 8;
  const u16* gB1 = Bm + (size_t)(bn * 128 + c1 * 16 + (l >> 2)) * 1024 + (l & 3) * 8;
  u16* lA0 = As + c0 * 512;
  u16* lA1 = As + c1 * 512;
  u16* lB0 = Bs + c0 * 512;
  u16* lB1 = Bs + c1 * 512;

  int aoff[4], boff[4];
#pragma unroll
  for (int mi = 0; mi < 4; ++mi) aoff[mi] = (wr + mi * 16 + lr) * 32 + lg * 8;
#pragma unroll
  for (int nj = 0; nj < 4; ++nj) boff[nj] = (wc + nj * 16 + lr) * 32 + lg * 8;

  for (int k0 = 0; k0 < 1024; k0 += 32) {
    load_lds16(gA0 + k0, lA0);
    load_lds16(gA1 + k0, lA1);
    load_lds16(gB0 + k0, lB0);
    load_lds16(gB1 + k0, lB1);
    __syncthreads();
    bf16x8 af[4], bff[4];
#pragma unroll
    for (int mi = 0; mi < 4; ++mi) af[mi] = lds_frag(&As[aoff[mi]]);
#pragma unroll
    for (int nj = 0; nj < 4; ++nj) bff[nj] = lds_frag(&Bs[boff[nj]]);
#pragma unroll
    for (int mi = 0; mi < 4; ++mi)
#pragma unroll
      for (int nj = 0; nj < 4; ++nj)
        acc[mi][nj] = mfma16(af[mi], bff[nj], acc[mi][nj]);
    __syncthreads();
  }
}

// ---------- QKV projection (UNCHANGED) ----------
__global__ __launch_bounds__(256) void proj_kernel(
    const u16* qb, const u16* kb, const u16* vb, const u16* Wq, const u16* Wk,
    const u16* Wv, const float* bq, const float* bk, const float* bv, u16* Qp,
    u16* Kp, u16* Vt) {
  __shared__ __align__(16) u16 As[128 * 32];
  __shared__ __align__(16) u16 Bs[128 * 32];
  const int z = blockIdx.z;
  const u16* A = z == 0 ? qb : z == 1 ? kb : vb;
  const u16* W = z == 0 ? Wq : z == 1 ? Wk : Wv;
  const float* bias = z == 0 ? bq : z == 1 ? bk : bv;

  f32x4 acc[4][4];
  gemm_core_1024(A, W, blockIdx.x, blockIdx.y, As, Bs, acc);

  const int tid = threadIdx.x;
  const int w = tid >> 6, l = tid & 63;
  const int lr = l & 15, lg = l >> 4;
  const int wr = (w >> 1) * 64, wc = (w & 1) * 64;
  const int b = (blockIdx.x * 128) >> 11;

#pragma unroll
  for (int nj = 0; nj < 4; ++nj) {
    const int col = blockIdx.y * 128 + wc + nj * 16 + lr;
    const float bb = bias[col];
    const int h = col >> 6, d = col & 63;
#pragma unroll
    for (int mi = 0; mi < 4; ++mi) {
      const int m0 = blockIdx.x * 128 + wr + mi * 16 + lg * 4;
      const int s0 = m0 & 2047;
      if (z < 2) {
        u16* dst = (z == 0) ? Qp : Kp;
#pragma unroll
        for (int r = 0; r < 4; ++r)
          dst[(((size_t)(b * 16 + h) * 2048) + s0 + r) * 64 + d] =
              f2bf(acc[mi][nj][r] + bb);
      } else {
        u16x4 pk;
        pk.x = f2bf(acc[mi][nj][0] + bb);
        pk.y = f2bf(acc[mi][nj][1] + bb);
        pk.z = f2bf(acc[mi][nj][2] + bb);
        pk.w = f2bf(acc[mi][nj][3] + bb);
        *(u16x4*)&Vt[(((size_t)(b * 16 + h) * 64) + d) * 2048 + s0] = pk;
      }
    }
  }
}

// ---------- output projection (UNCHANGED) ----------
__global__ __launch_bounds__(256) void outproj_kernel(const u16* O,
                                                      const u16* Wo,
                                                      const float* bo,
                                                      float* out) {
  __shared__ __align__(16) u16 As[128 * 32];
  __shared__ __align__(16) u16 Bs[128 * 32];
  f32x4 acc[4][4];
  gemm_core_1024(O, Wo, blockIdx.x, blockIdx.y, As, Bs, acc);

  const int tid = threadIdx.x;
  const int w = tid >> 6, l = tid & 63;
  const int lr = l & 15, lg = l >> 4;
  const int wr = (w >> 1) * 64, wc = (w & 1) * 64;
#pragma unroll
  for (int nj = 0; nj < 4; ++nj) {
    const int col = blockIdx.y * 128 + wc + nj * 16 + lr;
    const float bb = bo[col];
#pragma unroll
    for (int mi = 0; mi < 4; ++mi) {
      const int m0 = blockIdx.x * 128 + wr + mi * 16 + lg * 4;
#pragma unroll
      for (int r = 0; r < 4; ++r)
        out[(size_t)(m0 + r) * 1024 + col] = acc[mi][nj][r] + bb;
    }
  }
}

// ---------- flash attention v4: log2-domain softmax + defer-max + cvt_pk +
// double-buffered K/V LDS (1 barrier/tile). Swapped QK^T, 32x32x16. ----------
#define LDPK 72
#define NT 32  // 2048 / 64
__global__ __launch_bounds__(256) void attn_kernel(const u16* Qp, const u16* Kp,
                                                   const u16* Vt, u16* Ob) {
  __shared__ __align__(16) u16 Kl[2][64 * LDPK];
  __shared__ __align__(16) u16 Vl[2][64 * LDPK];

  const int tid = threadIdx.x, w = tid >> 6, l = tid & 63;
  const int q = l & 31, hi = l >> 5;
  const bool hib = hi != 0;
  const int bh = blockIdx.y;
  const int q0 = blockIdx.x * 128 + w * 32;
  const u16* Qh = Qp + (size_t)bh * 2048 * 64;
  const u16* Kh = Kp + (size_t)bh * 2048 * 64;
  const u16* Vh = Vt + (size_t)bh * 64 * 2048;

  const float SC2 = 0.1803368801f;  // 0.125 * log2(e)

  // Q B-fragments (held all kernel)
  bf16x8 qf[4];
#pragma unroll
  for (int ds = 0; ds < 4; ++ds)
    qf[ds] = *(const bf16x8*)&Qh[(size_t)(q0 + q) * 64 + ds * 16 + hi * 8];

  f32x16 o0 = zero16(), o1 = zero16();
  float m = -1.0e30f, ln = 0.f;

  // staging map: rows r0 (0..31) / r1 (32..63), col chunk g0
  const int r0 = tid >> 3, g0 = tid & 7;
  const int r1 = r0 + 32;

  int koff[2][4], voff[2][4];
#pragma unroll
  for (int kb = 0; kb < 2; ++kb)
#pragma unroll
    for (int ds = 0; ds < 4; ++ds)
      koff[kb][ds] = (kb * 32 + q) * LDPK + ds * 16 + hi * 8;
#pragma unroll
  for (int db = 0; db < 2; ++db)
#pragma unroll
    for (int ks = 0; ks < 4; ++ks)
      voff[db][ks] = (db * 32 + q) * LDPK + ks * 16 + hi * 8;

  // prologue: tile0 -> regs -> buf0; issue tile1 -> regs
  bf16x8 kv0 = *(const bf16x8*)&Kh[r0 * 64 + g0 * 8];
  bf16x8 kv1 = *(const bf16x8*)&Kh[r1 * 64 + g0 * 8];
  bf16x8 vv0 = *(const bf16x8*)&Vh[(size_t)r0 * 2048 + g0 * 8];
  bf16x8 vv1 = *(const bf16x8*)&Vh[(size_t)r1 * 2048 + g0 * 8];
  *(bf16x8*)&Kl[0][r0 * LDPK + g0 * 8] = kv0;
  *(bf16x8*)&Kl[0][r1 * LDPK + g0 * 8] = kv1;
  *(bf16x8*)&Vl[0][r0 * LDPK + g0 * 8] = vv0;
  *(bf16x8*)&Vl[0][r1 * LDPK + g0 * 8] = vv1;
  kv0 = *(const bf16x8*)&Kh[4096 + r0 * 64 + g0 * 8];
  kv1 = *(const bf16x8*)&Kh[4096 + r1 * 64 + g0 * 8];
  vv0 = *(const bf16x8*)&Vh[(size_t)r0 * 2048 + 64 + g0 * 8];
  vv1 = *(const bf16x8*)&Vh[(size_t)r1 * 2048 + 64 + g0 * 8];
  __syncthreads();

  for (int kt = 0; kt < NT; ++kt) {
    const int cur = kt & 1;
    const u16* Kc = Kl[cur];
    const u16* Vc = Vl[cur];

    // ---- S^T = K Q^T (raw scores) ----
    f32x16 c0 = zero16(), c1 = zero16();
#pragma unroll
    for (int ds = 0; ds < 4; ++ds)
      c0 = mfma32(lds_frag(&Kc[koff[0][ds]]), qf[ds], c0);
#pragma unroll
    for (int ds = 0; ds < 4; ++ds)
      c1 = mfma32(lds_frag(&Kc[koff[1][ds]]), qf[ds], c1);

    // ---- online softmax, log2 domain, defer-max (T13) ----
    float mx = c0[0];
#pragma unroll
    for (int r = 1; r < 16; ++r) mx = fmaxf(mx, c0[r]);
#pragma unroll
    for (int r = 0; r < 16; ++r) mx = fmaxf(mx, c1[r]);
    mx = fmaxf(mx, partner_f(mx));
    if (!__all(mx - m <= 64.0f)) {   // 64 raw = 8 score-units; p <= 2^11.6
      const float mnew = fmaxf(m, mx);
      const float a = exp2_hw((m - mnew) * SC2);
      m = mnew;
#pragma unroll
      for (int r = 0; r < 16; ++r) { o0[r] *= a; o1[r] *= a; }
      ln *= a;
    }
    const float m2 = m * SC2;
    float p0[16], p1[16];
    float rs = 0.f;
#pragma unroll
    for (int r = 0; r < 16; ++r) {
      p0[r] = exp2_hw(__builtin_fmaf(c0[r], SC2, -m2));
      p1[r] = exp2_hw(__builtin_fmaf(c1[r], SC2, -m2));
      rs += p0[r] + p1[r];
    }
    rs += partner_f(rs);
    ln += rs;

    // ---- write tile kt+1 regs -> other buffer (its readers passed barrier) ----
    if (kt + 1 < NT) {
      u16* Kn = Kl[cur ^ 1];
      u16* Vn = Vl[cur ^ 1];
      *(bf16x8*)&Kn[r0 * LDPK + g0 * 8] = kv0;
      *(bf16x8*)&Kn[r1 * LDPK + g0 * 8] = kv1;
      *(bf16x8*)&Vn[r0 * LDPK + g0 * 8] = vv0;
      *(bf16x8*)&Vn[r1 * LDPK + g0 * 8] = vv1;
    }
    // ---- issue tile kt+2 global loads (T14: latency under PV) ----
    if (kt + 2 < NT) {
      const int ko = (kt + 2) * 4096, vo = (kt + 2) * 64;
      kv0 = *(const bf16x8*)&Kh[ko + r0 * 64 + g0 * 8];
      kv1 = *(const bf16x8*)&Kh[ko + r1 * 64 + g0 * 8];
      vv0 = *(const bf16x8*)&Vh[(size_t)r0 * 2048 + vo + g0 * 8];
      vv1 = *(const bf16x8*)&Vh[(size_t)r1 * 2048 + vo + g0 * 8];
    }

    // ---- P -> bf16 pair-words (1-inst cvt_pk), V1-pswap(emul) -> B-frags ----
    uint32_t wv[16];
#pragma unroll
    for (int i = 0; i < 8; ++i) {
      wv[i]     = cvtpk(p0[2 * i], p0[2 * i + 1]);
      wv[8 + i] = cvtpk(p1[2 * i], p1[2 * i + 1]);
    }
    bf16x8 pa[4];
#pragma unroll
    for (int ks = 0; ks < 4; ++ks) {
      const int base = (ks >> 1) * 8 + 4 * (ks & 1);
      uint32_t x0 = wv[base],     y0 = wv[base + 2];
      uint32_t x1 = wv[base + 1], y1 = wv[base + 3];
      pswap_emul(x0, y0, hib);
      pswap_emul(x1, y1, hib);
      union { uint32_t u[4]; bf16x8 v; } cvt;
      cvt.u[0] = x0; cvt.u[1] = x1; cvt.u[2] = y0; cvt.u[3] = y1;
      pa[ks] = cvt.v;
    }

    // ---- O^T += V^T P^T ----
#pragma unroll
    for (int ks = 0; ks < 4; ++ks)
      o0 = mfma32(lds_frag(&Vc[voff[0][ks]]), pa[ks], o0);
#pragma unroll
    for (int ks = 0; ks < 4; ++ks)
      o1 = mfma32(lds_frag(&Vc[voff[1][ks]]), pa[ks], o1);

    __syncthreads();  // buf[cur] reads done; buf[cur^1] writes visible
  }

  // ---- epilogue: lane holds row s = q0+q; d = db*32 + (r&3)+8*(r>>2)+4*hi ----
  const int b2 = bh >> 4, h = bh & 15;
  const float inv = 1.0f / ln;
  u16* orow = Ob + ((size_t)(b2 * 2048 + q0 + q)) * 1024 + h * 64;
#pragma unroll
  for (int g = 0; g < 4; ++g) {
    u16x4 pk;
    pk.x = f2bf(o0[4 * g + 0] * inv);
    pk.y = f2bf(o0[4 * g + 1] * inv);
    pk.z = f2bf(o0[4 * g + 2] * inv);
    pk.w = f2bf(o0[4 * g + 3] * inv);
    *(u16x4*)&orow[8 * g + 4 * hi] = pk;
  }
#pragma unroll
  for (int g = 0; g < 4; ++g) {
    u16x4 pk;
    pk.x = f2bf(o1[4 * g + 0] * inv);
    pk.y = f2bf(o1[4 * g + 1] * inv);
    pk.z = f2bf(o1[4 * g + 2] * inv);
    pk.w = f2bf(o1[4 * g + 3] * inv);
    *(u16x4*)&orow[32 + 8 * g + 4 * hi] = pk;
  }
}

// ---------- launcher ----------
extern "C" void kernel_launch(void* const* d_in, const int* in_sizes, int n_in,
                              void* d_out, int out_size, void* d_ws,
                              size_t ws_size, hipStream_t stream) {
  const float* q  = (const float*)d_in[0];
  const float* k  = (const float*)d_in[1];
  const float* v  = (const float*)d_in[2];
  const float* Wq = (const float*)d_in[3];
  const float* bq = (const float*)d_in[4];
  const float* Wk = (const float*)d_in[5];
  const float* bk = (const float*)d_in[6];
  const float* Wv = (const float*)d_in[7];
  const float* bv = (const float*)d_in[8];
  const float* Wo = (const float*)d_in[9];
  const float* bo = (const float*)d_in[10];
  float* out = (float*)d_out;

  u16* ws = (u16*)d_ws;
  u16* qb  = ws;              // [8192,1024] bf16
  u16* kb  = qb + NBIG;
  u16* vb  = kb + NBIG;
  u16* Wqb = vb + NBIG;       // [1024,1024] bf16 x4
  u16* Wkb = Wqb + NW;
  u16* Wvb = Wkb + NW;
  u16* Wob = Wvb + NW;
  u16* Qp  = Wob + NW;        // [B,H,S,64]
  u16* Kp  = Qp + NBIG;       // [B,H,S,64]
  u16* Vt  = Kp + NBIG;       // [B,H,64,S]
  u16* O   = qb;              // alias: qb dead after proj_kernel

  cvt_kernel<<<dim3(8192, 7, 1), 256, 0, stream>>>(q, k, v, Wq, Wk, Wv, Wo, qb,
                                                   kb, vb, Wqb, Wkb, Wvb, Wob);
  proj_kernel<<<dim3(64, 8, 3), 256, 0, stream>>>(qb, kb, vb, Wqb, Wkb, Wvb,
                                                  bq, bk, bv, Qp, Kp, Vt);
  attn_kernel<<<dim3(16, 64, 1), 256, 0, stream>>>(Qp, Kp, Vt, O);
  outproj_kernel<<<dim3(64, 8, 1), 256, 0, stream>>>(O, Wob, bo, out);
}

// Round 6
// 235.630 us; speedup vs baseline: 1.5007x; 1.0126x over previous
//
#include <hip/hip_runtime.h>
#include <stdint.h>

#define DEVI static __device__ __forceinline__

typedef __attribute__((ext_vector_type(4))) float f32x4;
typedef __attribute__((ext_vector_type(16))) float f32x16;
typedef __attribute__((ext_vector_type(8))) __bf16 bf16x8;
typedef __attribute__((ext_vector_type(4))) uint16_t u16x4;
typedef uint16_t u16;

// ---------- helpers ----------
DEVI u16 f2bf(float f) {  // round-to-nearest-even fp32 -> bf16
  union { float f; uint32_t u; } v; v.f = f;
  uint32_t r = v.u + 0x7FFFu + ((v.u >> 16) & 1u);
  return (u16)(r >> 16);
}

DEVI f32x4 mfma16(bf16x8 a, bf16x8 b, f32x4 c) {
  return __builtin_amdgcn_mfma_f32_16x16x32_bf16(a, b, c, 0, 0, 0);
}

DEVI f32x16 mfma32(bf16x8 a, bf16x8 b, f32x16 c) {
  return __builtin_amdgcn_mfma_f32_32x32x16_bf16(a, b, c, 0, 0, 0);
}

DEVI void load_lds16(const void* g, void* l) {  // async global->LDS, 16B/lane
  __builtin_amdgcn_global_load_lds(
      (const __attribute__((address_space(1))) void*)g,
      (__attribute__((address_space(3))) void*)l, 16, 0, 0);
}

DEVI bf16x8 lds_frag(const u16* p) { return *(const bf16x8*)p; }

DEVI f32x16 zero16() {
  f32x16 z;
#pragma unroll
  for (int i = 0; i < 16; ++i) z[i] = 0.f;
  return z;
}

// hardware exp2 (1 instruction)
DEVI float exp2_hw(float x) {
  float r;
  asm("v_exp_f32 %0, %1" : "=v"(r) : "v"(x));
  return r;
}

// pack 2 f32 -> bf16x2 word in ONE instruction
DEVI uint32_t cvtpk(float lo, float hi) {
  uint32_t r;
  asm("v_cvt_pk_bf16_f32 %0, %1, %2" : "=v"(r) : "v"(lo), "v"(hi));
  return r;
}

// cross-half exchange via shfl (for scalar reduces; coalescing-proof)
DEVI float partner_f(float x) { return __shfl_xor(x, 32, 64); }

// REAL v_permlane32_swap_b32: exchanges a.hi-lanes <-> b.lo-lanes.
// ONLY safe when a and b hold DISTINCT values (same-value operands may be
// register-coalesced -> swap-with-self; that was the round-3 bug).
DEVI void pswap_asm(uint32_t& a, uint32_t& b) {
  asm("v_permlane32_swap_b32 %0, %1" : "+v"(a), "+v"(b));
}

// ---------- fp32 -> bf16 conversion (7 segments) ----------
#define NBIG (4 * 2048 * 1024)
#define NW (1024 * 1024)

__global__ __launch_bounds__(256) void cvt_kernel(
    const float* q, const float* k, const float* v, const float* Wq,
    const float* Wk, const float* Wv, const float* Wo, u16* qb, u16* kb,
    u16* vb, u16* Wqb, u16* Wkb, u16* Wvb, u16* Wob) {
  const float* src;
  u16* dst;
  int n;
  switch (blockIdx.y) {
    case 0: src = q;  dst = qb;  n = NBIG; break;
    case 1: src = k;  dst = kb;  n = NBIG; break;
    case 2: src = v;  dst = vb;  n = NBIG; break;
    case 3: src = Wq; dst = Wqb; n = NW;   break;
    case 4: src = Wk; dst = Wkb; n = NW;   break;
    case 5: src = Wv; dst = Wvb; n = NW;   break;
    default: src = Wo; dst = Wob; n = NW;  break;
  }
  int i = (blockIdx.x * 256 + threadIdx.x) * 4;
  if (i >= n) return;
  float4 f = *(const float4*)&src[i];
  u16x4 o;
  o.x = f2bf(f.x); o.y = f2bf(f.y); o.z = f2bf(f.z); o.w = f2bf(f.w);
  *(u16x4*)&dst[i] = o;
}

// ---------- GEMM core (m97 structure, UNCHANGED) ----------
DEVI void gemm_core_1024(const u16* __restrict__ A, const u16* __restrict__ Bm,
                         int bm, int bn, u16* As, u16* Bs, f32x4 acc[4][4]) {
  const int tid = threadIdx.x;
  const int w = tid >> 6, l = tid & 63;
  const int lr = l & 15, lg = l >> 4;
  const int wr = (w >> 1) * 64, wc = (w & 1) * 64;

  for (int i = 0; i < 4; ++i)
    for (int j = 0; j < 4; ++j) acc[i][j] = (f32x4){0.f, 0.f, 0.f, 0.f};

  const int c0 = 2 * w, c1 = 2 * w + 1;
  const u16* gA0 = A + (size_t)(bm * 128 + c0 * 16 + (l >> 2)) * 1024 + (l & 3) * 8;
  const u16* gA1 = A + (size_t)(bm * 128 + c1 * 16 + (l >> 2)) * 1024 + (l & 3) * 8;
  const u16* gB0 = Bm + (size_t)(bn * 128 + c0 * 16 + (l >> 2)) * 1024 + (l & 3) * 8;
  const u16* gB1 = Bm + (size_t)(bn * 128 + c1 * 16 + (l >> 2)) * 1024 + (l & 3) * 8;
  u16* lA0 = As + c0 * 512;
  u16* lA1 = As + c1 * 512;
  u16* lB0 = Bs + c0 * 512;
  u16* lB1 = Bs + c1 * 512;

  int aoff[4], boff[4];
#pragma unroll
  for (int mi = 0; mi < 4; ++mi) aoff[mi] = (wr + mi * 16 + lr) * 32 + lg * 8;
#pragma unroll
  for (int nj = 0; nj < 4; ++nj) boff[nj] = (wc + nj * 16 + lr) * 32 + lg * 8;

  for (int k0 = 0; k0 < 1024; k0 += 32) {
    load_lds16(gA0 + k0, lA0);
    load_lds16(gA1 + k0, lA1);
    load_lds16(gB0 + k0, lB0);
    load_lds16(gB1 + k0, lB1);
    __syncthreads();
    bf16x8 af[4], bff[4];
#pragma unroll
    for (int mi = 0; mi < 4; ++mi) af[mi] = lds_frag(&As[aoff[mi]]);
#pragma unroll
    for (int nj = 0; nj < 4; ++nj) bff[nj] = lds_frag(&Bs[boff[nj]]);
#pragma unroll
    for (int mi = 0; mi < 4; ++mi)
#pragma unroll
      for (int nj = 0; nj < 4; ++nj)
        acc[mi][nj] = mfma16(af[mi], bff[nj], acc[mi][nj]);
    __syncthreads();
  }
}

// ---------- QKV projection (UNCHANGED) ----------
__global__ __launch_bounds__(256) void proj_kernel(
    const u16* qb, const u16* kb, const u16* vb, const u16* Wq, const u16* Wk,
    const u16* Wv, const float* bq, const float* bk, const float* bv, u16* Qp,
    u16* Kp, u16* Vt) {
  __shared__ __align__(16) u16 As[128 * 32];
  __shared__ __align__(16) u16 Bs[128 * 32];
  const int z = blockIdx.z;
  const u16* A = z == 0 ? qb : z == 1 ? kb : vb;
  const u16* W = z == 0 ? Wq : z == 1 ? Wk : Wv;
  const float* bias = z == 0 ? bq : z == 1 ? bk : bv;

  f32x4 acc[4][4];
  gemm_core_1024(A, W, blockIdx.x, blockIdx.y, As, Bs, acc);

  const int tid = threadIdx.x;
  const int w = tid >> 6, l = tid & 63;
  const int lr = l & 15, lg = l >> 4;
  const int wr = (w >> 1) * 64, wc = (w & 1) * 64;
  const int b = (blockIdx.x * 128) >> 11;

#pragma unroll
  for (int nj = 0; nj < 4; ++nj) {
    const int col = blockIdx.y * 128 + wc + nj * 16 + lr;
    const float bb = bias[col];
    const int h = col >> 6, d = col & 63;
#pragma unroll
    for (int mi = 0; mi < 4; ++mi) {
      const int m0 = blockIdx.x * 128 + wr + mi * 16 + lg * 4;
      const int s0 = m0 & 2047;
      if (z < 2) {
        u16* dst = (z == 0) ? Qp : Kp;
#pragma unroll
        for (int r = 0; r < 4; ++r)
          dst[(((size_t)(b * 16 + h) * 2048) + s0 + r) * 64 + d] =
              f2bf(acc[mi][nj][r] + bb);
      } else {
        u16x4 pk;
        pk.x = f2bf(acc[mi][nj][0] + bb);
        pk.y = f2bf(acc[mi][nj][1] + bb);
        pk.z = f2bf(acc[mi][nj][2] + bb);
        pk.w = f2bf(acc[mi][nj][3] + bb);
        *(u16x4*)&Vt[(((size_t)(b * 16 + h) * 64) + d) * 2048 + s0] = pk;
      }
    }
  }
}

// ---------- output projection (UNCHANGED) ----------
__global__ __launch_bounds__(256) void outproj_kernel(const u16* O,
                                                      const u16* Wo,
                                                      const float* bo,
                                                      float* out) {
  __shared__ __align__(16) u16 As[128 * 32];
  __shared__ __align__(16) u16 Bs[128 * 32];
  f32x4 acc[4][4];
  gemm_core_1024(O, Wo, blockIdx.x, blockIdx.y, As, Bs, acc);

  const int tid = threadIdx.x;
  const int w = tid >> 6, l = tid & 63;
  const int lr = l & 15, lg = l >> 4;
  const int wr = (w >> 1) * 64, wc = (w & 1) * 64;
#pragma unroll
  for (int nj = 0; nj < 4; ++nj) {
    const int col = blockIdx.y * 128 + wc + nj * 16 + lr;
    const float bb = bo[col];
#pragma unroll
    for (int mi = 0; mi < 4; ++mi) {
      const int m0 = blockIdx.x * 128 + wr + mi * 16 + lg * 4;
#pragma unroll
      for (int r = 0; r < 4; ++r)
        out[(size_t)(m0 + r) * 1024 + col] = acc[mi][nj][r] + bb;
    }
  }
}

// ---------- flash attention v5: tree reduces + real permlane P-pack + setprio
// (log2 softmax, defer-max, double-buffered K/V, swapped QK^T 32x32x16) ------
#define LDPK 72
#define NT 32  // 2048 / 64
__global__ __launch_bounds__(256) void attn_kernel(const u16* Qp, const u16* Kp,
                                                   const u16* Vt, u16* Ob) {
  __shared__ __align__(16) u16 Kl[2][64 * LDPK];
  __shared__ __align__(16) u16 Vl[2][64 * LDPK];

  const int tid = threadIdx.x, w = tid >> 6, l = tid & 63;
  const int q = l & 31, hi = l >> 5;
  const int bh = blockIdx.y;
  const int q0 = blockIdx.x * 128 + w * 32;
  const u16* Qh = Qp + (size_t)bh * 2048 * 64;
  const u16* Kh = Kp + (size_t)bh * 2048 * 64;
  const u16* Vh = Vt + (size_t)bh * 64 * 2048;

  const float SC2 = 0.1803368801f;  // 0.125 * log2(e)

  // Q B-fragments (held all kernel)
  bf16x8 qf[4];
#pragma unroll
  for (int ds = 0; ds < 4; ++ds)
    qf[ds] = *(const bf16x8*)&Qh[(size_t)(q0 + q) * 64 + ds * 16 + hi * 8];

  f32x16 o0 = zero16(), o1 = zero16();
  float m = -1.0e30f, ln = 0.f;

  // staging map: rows r0 (0..31) / r1 (32..63), col chunk g0
  const int r0 = tid >> 3, g0 = tid & 7;
  const int r1 = r0 + 32;

  int koff[2][4], voff[2][4];
#pragma unroll
  for (int kb = 0; kb < 2; ++kb)
#pragma unroll
    for (int ds = 0; ds < 4; ++ds)
      koff[kb][ds] = (kb * 32 + q) * LDPK + ds * 16 + hi * 8;
#pragma unroll
  for (int db = 0; db < 2; ++db)
#pragma unroll
    for (int ks = 0; ks < 4; ++ks)
      voff[db][ks] = (db * 32 + q) * LDPK + ks * 16 + hi * 8;

  // prologue: tile0 -> buf0; tile1 -> regs; running pointers at tile2
  bf16x8 kv0 = *(const bf16x8*)&Kh[r0 * 64 + g0 * 8];
  bf16x8 kv1 = *(const bf16x8*)&Kh[r1 * 64 + g0 * 8];
  bf16x8 vv0 = *(const bf16x8*)&Vh[(size_t)r0 * 2048 + g0 * 8];
  bf16x8 vv1 = *(const bf16x8*)&Vh[(size_t)r1 * 2048 + g0 * 8];
  *(bf16x8*)&Kl[0][r0 * LDPK + g0 * 8] = kv0;
  *(bf16x8*)&Kl[0][r1 * LDPK + g0 * 8] = kv1;
  *(bf16x8*)&Vl[0][r0 * LDPK + g0 * 8] = vv0;
  *(bf16x8*)&Vl[0][r1 * LDPK + g0 * 8] = vv1;
  kv0 = *(const bf16x8*)&Kh[4096 + r0 * 64 + g0 * 8];
  kv1 = *(const bf16x8*)&Kh[4096 + r1 * 64 + g0 * 8];
  vv0 = *(const bf16x8*)&Vh[(size_t)r0 * 2048 + 64 + g0 * 8];
  vv1 = *(const bf16x8*)&Vh[(size_t)r1 * 2048 + 64 + g0 * 8];
  const u16* gk0 = Kh + 2 * 4096 + r0 * 64 + g0 * 8;
  const u16* gk1 = Kh + 2 * 4096 + r1 * 64 + g0 * 8;
  const u16* gv0 = Vh + (size_t)r0 * 2048 + 2 * 64 + g0 * 8;
  const u16* gv1 = Vh + (size_t)r1 * 2048 + 2 * 64 + g0 * 8;
  __syncthreads();

  for (int kt = 0; kt < NT; ++kt) {
    const int cur = kt & 1;
    const u16* Kc = Kl[cur];
    const u16* Vc = Vl[cur];

    // ---- S^T = K Q^T (raw scores) ----
    f32x16 c0 = zero16(), c1 = zero16();
    __builtin_amdgcn_s_setprio(1);
#pragma unroll
    for (int ds = 0; ds < 4; ++ds)
      c0 = mfma32(lds_frag(&Kc[koff[0][ds]]), qf[ds], c0);
#pragma unroll
    for (int ds = 0; ds < 4; ++ds)
      c1 = mfma32(lds_frag(&Kc[koff[1][ds]]), qf[ds], c1);
    __builtin_amdgcn_s_setprio(0);

    // ---- online softmax, log2 domain, defer-max; TREE reduces ----
    float tm[16];
#pragma unroll
    for (int r = 0; r < 16; ++r) tm[r] = fmaxf(c0[r], c1[r]);
#pragma unroll
    for (int s = 8; s > 0; s >>= 1)
#pragma unroll
      for (int r = 0; r < s; ++r) tm[r] = fmaxf(tm[r], tm[r + s]);
    const float mx = fmaxf(tm[0], partner_f(tm[0]));
    if (!__all(mx - m <= 64.0f)) {   // 64 raw = 8 score-units
      const float mnew = fmaxf(m, mx);
      const float a = exp2_hw((m - mnew) * SC2);
      m = mnew;
#pragma unroll
      for (int r = 0; r < 16; ++r) { o0[r] *= a; o1[r] *= a; }
      ln *= a;
    }
    const float m2 = m * SC2;
    float p0[16], p1[16];
#pragma unroll
    for (int r = 0; r < 16; ++r) {
      p0[r] = exp2_hw(__builtin_fmaf(c0[r], SC2, -m2));
      p1[r] = exp2_hw(__builtin_fmaf(c1[r], SC2, -m2));
    }
    float ts[16];
#pragma unroll
    for (int r = 0; r < 16; ++r) ts[r] = p0[r] + p1[r];
#pragma unroll
    for (int s = 8; s > 0; s >>= 1)
#pragma unroll
      for (int r = 0; r < s; ++r) ts[r] += ts[r + s];
    ln += ts[0] + partner_f(ts[0]);

    // ---- write tile kt+1 regs -> other buffer ----
    if (kt + 1 < NT) {
      u16* Kn = Kl[cur ^ 1];
      u16* Vn = Vl[cur ^ 1];
      *(bf16x8*)&Kn[r0 * LDPK + g0 * 8] = kv0;
      *(bf16x8*)&Kn[r1 * LDPK + g0 * 8] = kv1;
      *(bf16x8*)&Vn[r0 * LDPK + g0 * 8] = vv0;
      *(bf16x8*)&Vn[r1 * LDPK + g0 * 8] = vv1;
    }
    // ---- issue tile kt+2 global loads (running pointers) ----
    if (kt + 2 < NT) {
      kv0 = *(const bf16x8*)gk0;
      kv1 = *(const bf16x8*)gk1;
      vv0 = *(const bf16x8*)gv0;
      vv1 = *(const bf16x8*)gv1;
      gk0 += 4096; gk1 += 4096; gv0 += 64; gv1 += 64;
    }

    // ---- P -> bf16 pair-words (cvt_pk), REAL permlane swap -> B-frags ----
    uint32_t wv[16];
#pragma unroll
    for (int i = 0; i < 8; ++i) {
      wv[i]     = cvtpk(p0[2 * i], p0[2 * i + 1]);
      wv[8 + i] = cvtpk(p1[2 * i], p1[2 * i + 1]);
    }
    bf16x8 pa[4];
#pragma unroll
    for (int ks = 0; ks < 4; ++ks) {
      const int base = (ks >> 1) * 8 + 4 * (ks & 1);
      uint32_t x0 = wv[base],     y0 = wv[base + 2];
      uint32_t x1 = wv[base + 1], y1 = wv[base + 3];
      pswap_asm(x0, y0);   // distinct values: no coalescing hazard
      pswap_asm(x1, y1);
      union { uint32_t u[4]; bf16x8 v; } cvt;
      cvt.u[0] = x0; cvt.u[1] = x1; cvt.u[2] = y0; cvt.u[3] = y1;
      pa[ks] = cvt.v;
    }

    // ---- O^T += V^T P^T ----
    __builtin_amdgcn_s_setprio(1);
#pragma unroll
    for (int ks = 0; ks < 4; ++ks)
      o0 = mfma32(lds_frag(&Vc[voff[0][ks]]), pa[ks], o0);
#pragma unroll
    for (int ks = 0; ks < 4; ++ks)
      o1 = mfma32(lds_frag(&Vc[voff[1][ks]]), pa[ks], o1);
    __builtin_amdgcn_s_setprio(0);

    __syncthreads();  // buf[cur] reads done; buf[cur^1] writes visible
  }

  // ---- epilogue ----
  const int b2 = bh >> 4, h = bh & 15;
  const float inv = 1.0f / ln;
  u16* orow = Ob + ((size_t)(b2 * 2048 + q0 + q)) * 1024 + h * 64;
#pragma unroll
  for (int g = 0; g < 4; ++g) {
    u16x4 pk;
    pk.x = f2bf(o0[4 * g + 0] * inv);
    pk.y = f2bf(o0[4 * g + 1] * inv);
    pk.z = f2bf(o0[4 * g + 2] * inv);
    pk.w = f2bf(o0[4 * g + 3] * inv);
    *(u16x4*)&orow[8 * g + 4 * hi] = pk;
  }
#pragma unroll
  for (int g = 0; g < 4; ++g) {
    u16x4 pk;
    pk.x = f2bf(o1[4 * g + 0] * inv);
    pk.y = f2bf(o1[4 * g + 1] * inv);
    pk.z = f2bf(o1[4 * g + 2] * inv);
    pk.w = f2bf(o1[4 * g + 3] * inv);
    *(u16x4*)&orow[32 + 8 * g + 4 * hi] = pk;
  }
}

// ---------- launcher ----------
extern "C" void kernel_launch(void* const* d_in, const int* in_sizes, int n_in,
                              void* d_out, int out_size, void* d_ws,
                              size_t ws_size, hipStream_t stream) {
  const float* q  = (const float*)d_in[0];
  const float* k  = (const float*)d_in[1];
  const float* v  = (const float*)d_in[2];
  const float* Wq = (const float*)d_in[3];
  const float* bq = (const float*)d_in[4];
  const float* Wk = (const float*)d_in[5];
  const float* bk = (const float*)d_in[6];
  const float* Wv = (const float*)d_in[7];
  const float* bv = (const float*)d_in[8];
  const float* Wo = (const float*)d_in[9];
  const float* bo = (const float*)d_in[10];
  float* out = (float*)d_out;

  u16* ws = (u16*)d_ws;
  u16* qb  = ws;              // [8192,1024] bf16
  u16* kb  = qb + NBIG;
  u16* vb  = kb + NBIG;
  u16* Wqb = vb + NBIG;       // [1024,1024] bf16 x4
  u16* Wkb = Wqb + NW;
  u16* Wvb = Wkb + NW;
  u16* Wob = Wvb + NW;
  u16* Qp  = Wob + NW;        // [B,H,S,64]
  u16* Kp  = Qp + NBIG;       // [B,H,S,64]
  u16* Vt  = Kp + NBIG;       // [B,H,64,S]
  u16* O   = qb;              // alias: qb dead after proj_kernel

  cvt_kernel<<<dim3(8192, 7, 1), 256, 0, stream>>>(q, k, v, Wq, Wk, Wv, Wo, qb,
                                                   kb, vb, Wqb, Wkb, Wvb, Wob);
  proj_kernel<<<dim3(64, 8, 3), 256, 0, stream>>>(qb, kb, vb, Wqb, Wkb, Wvb,
                                                  bq, bk, bv, Qp, Kp, Vt);
  attn_kernel<<<dim3(16, 64, 1), 256, 0, stream>>>(Qp, Kp, Vt, O);
  outproj_kernel<<<dim3(64, 8, 1), 256, 0, stream>>>(O, Wob, bo, out);
}